// Round 15
// baseline (98.683 us; speedup 1.0000x reference)
//
#include <hip/hip_runtime.h>

#define N_NODES 25000
#define N_EDGES 200000
#define NC 32
#define DMAX 64            // bucket capacity; degrees are Poisson(8), max ~25

typedef unsigned int u32;
typedef u32   u32x4 __attribute__((ext_vector_type(4)));
typedef u32   u32x2 __attribute__((ext_vector_type(2)));
typedef float f32x2 __attribute__((ext_vector_type(2)));
typedef float f32x4 __attribute__((ext_vector_type(4)));
typedef u32x4 u32x4_a4 __attribute__((aligned(4)));
typedef u32x2 u32x2_a4 __attribute__((aligned(4)));
typedef f32x2 f32x2_a4 __attribute__((aligned(4)));
typedef f32x4 f32x4_a4 __attribute__((aligned(4)));

// ---------------------------------------------------------------------------
// Workspace layout (bytes)
//   Hm     : [25000][32 ch][14 ushort] bf16 (slot0 = G = H0+tr(H2))
//   slots  : [25000][64] int2   (.x = edge id, .y = recv id)
//   cursor : [25000] int
// ---------------------------------------------------------------------------
static constexpr size_t HM_BYTES   = (size_t)N_NODES * NC * 28;        // 22,400,000
static constexpr size_t SLOTS_OFF  = HM_BYTES;
static constexpr size_t CURSOR_OFF = SLOTS_OFF + (size_t)N_NODES * DMAX * 8;
static constexpr size_t WS_NEEDED  = CURSOR_OFF + (size_t)N_NODES * 4; // ~35.3 MB

__device__ __forceinline__ unsigned short f2b(float f) {
    union { float f; unsigned u; } v; v.f = f;
    unsigned r = v.u + 0x7FFFu + ((v.u >> 16) & 1u);
    return (unsigned short)(r >> 16);
}
__device__ __forceinline__ float blo(u32 u) { return __uint_as_float(u << 16); }
__device__ __forceinline__ float bhi(u32 u) { return __uint_as_float(u & 0xFFFF0000u); }

// ---------------------------------------------------------------------------
// Per-edge contraction, G-form (G = H0 + tr(H2) precomputed at mix time)
// ---------------------------------------------------------------------------
__device__ __forceinline__ void edge_contract_g(
    float G, const float H1v[3], const float H2v[9],
    float a0, const float a1[3], const float a2[9],
    float& acc0, float acc1[3], float acc2[9])
{
    const float t2 = a2[0] + a2[4] + a2[8];
    const float s  = a0 + t2;

    float sA[9], S2[9];
#pragma unroll
    for (int a = 0; a < 3; ++a)
#pragma unroll
        for (int b = 0; b < 3; ++b) {
            sA[a*3+b] = a2[a*3+b] + a2[b*3+a];
            S2[a*3+b] = H2v[a*3+b] + H2v[b*3+a];
        }

    float v0 = G * s;
#pragma unroll
    for (int a = 0; a < 3; ++a) v0 += H1v[a] * a1[a];
#pragma unroll
    for (int k = 0; k < 9; ++k) v0 += H2v[k] * sA[k];
    acc0 += v0;

#pragma unroll
    for (int a = 0; a < 3; ++a) {
        float v = G * a1[a] + H1v[a] * s;
#pragma unroll
        for (int b = 0; b < 3; ++b)
            v += sA[a*3+b] * H1v[b] + S2[a*3+b] * a1[b];
        acc1[a] += v;
    }

#pragma unroll
    for (int a = 0; a < 3; ++a)
#pragma unroll
        for (int b = 0; b < 3; ++b) {
            float v = G * a2[a*3+b] + H1v[a] * a1[b] + H2v[a*3+b] * s;
#pragma unroll
            for (int d = 0; d < 3; ++d)
                v += S2[a*3+d] * sA[d*3+b];
            acc2[a*3+b] += v;
        }
}

// original form for the no-workspace fallback
__device__ __forceinline__ void edge_contract(
    float H0v, const float H1v[3], const float H2v[9],
    float a0, const float a1[3], const float a2[9],
    float& acc0, float acc1[3], float acc2[9])
{
    const float T2 = H2v[0] + H2v[4] + H2v[8];
    edge_contract_g(H0v + T2, H1v, H2v, a0, a1, a2, acc0, acc1, acc2);
}

// ---------------------------------------------------------------------------
// Fused kernel: blocks [0,3125) = per-node channel mixing -> bf16 Hm
//               blocks [3125,3907) = bucket scatter of edges by send node
// cursor[] must be zeroed before this kernel (hipMemsetAsync).
// r12 layout: 8 nodes/block, 1 ch/thread, h_lds stride 16 floats/j — a wave
// spans 2 nodes (node stride 512 floats, bank-aligned) -> 2-way LDS aliasing
// which is FREE. r13's 16-nodes/block variant made it 4 nodes/wave -> 4-way
// conflict on every b128 read (3.8M SQ_LDS_BANK_CONFLICT, mix 25->64 µs).
// Do not raise nodes/wave past 2 with this bank-aligned stride.
// ---------------------------------------------------------------------------
__global__ __launch_bounds__(256) void mixscatter_kernel(
    const float* __restrict__ h0, const float* __restrict__ h1,
    const float* __restrict__ h2, const float* __restrict__ W,
    const int* __restrict__ ei,
    char* __restrict__ Hm, int2* __restrict__ slots, int* __restrict__ cursor)
{
    const int tid = threadIdx.x;

    if (blockIdx.x >= 3125) {            // ---- scatter part ----
        const int e = (blockIdx.x - 3125) * 256 + tid;
        if (e < N_EDGES) {
            const int send = ei[e];
            const int pos  = atomicAdd(&cursor[send], 1);
            if (pos < DMAX) {            // Poisson(8): deg>64 has P~1e-40
                int2 sl; sl.x = e; sl.y = ei[N_EDGES + e];
                slots[send * DMAX + pos] = sl;
            }
        }
        return;
    }

    // ---- mix part ----
    __shared__ float Wt[3 * 32 * 32];                 // Wt[r][j][i] = W[r][i][j]
    __shared__ __align__(16) float h_lds[8 * 512];    // [node][j*16 + p], p<13

    const int n0 = blockIdx.x * 8;

#pragma unroll
    for (int k = 0; k < 12; ++k) {
        int q = tid + k * 256;           // q = r*1024 + j*32 + i
        int r = q >> 10;
        int j = (q >> 5) & 31;
        int i = q & 31;
        Wt[q] = W[r * 1024 + i * 32 + j];
    }

    {
        int idx = tid;                   // h0: 256 floats
        h_lds[(idx >> 5) * 512 + (idx & 31) * 16 + 0] = h0[(size_t)n0 * 32 + idx];
    }
#pragma unroll
    for (int k = 0; k < 3; ++k) {        // h1: 768 floats
        int idx = tid + k * 256;
        int ln = idx / 96, rem = idx % 96;
        h_lds[ln * 512 + (rem / 3) * 16 + 1 + (rem % 3)] = h1[(size_t)n0 * 96 + idx];
    }
#pragma unroll
    for (int k = 0; k < 9; ++k) {        // h2: 2304 floats
        int idx = tid + k * 256;
        int ln = idx / 288, rem = idx % 288;
        h_lds[ln * 512 + (rem / 9) * 16 + 4 + (rem % 9)] = h2[(size_t)n0 * 288 + idx];
    }
    __syncthreads();

    const int ln = tid >> 5;
    const int i  = tid & 31;
    const int n  = n0 + ln;

    float acc[13];
#pragma unroll
    for (int p = 0; p < 13; ++p) acc[p] = 0.f;

#pragma unroll 4
    for (int j = 0; j < 32; ++j) {
        const float w0 = Wt[          j * 32 + i];
        const float w1 = Wt[1024 +    j * 32 + i];
        const float w2 = Wt[2048 +    j * 32 + i];
        const float* hv = &h_lds[ln * 512 + j * 16];
        const f32x4 qa = *(const f32x4*)(hv);        // p 0..3
        const f32x4 qb = *(const f32x4*)(hv + 4);    // p 4..7
        const f32x4 qc = *(const f32x4*)(hv + 8);    // p 8..11
        const float hc = hv[12];                     // p 12
        acc[0]  += w0 * qa.x;
        acc[1]  += w1 * qa.y;  acc[2]  += w1 * qa.z;  acc[3]  += w1 * qa.w;
        acc[4]  += w2 * qb.x;  acc[5]  += w2 * qb.y;  acc[6]  += w2 * qb.z;
        acc[7]  += w2 * qb.w;  acc[8]  += w2 * qc.x;  acc[9]  += w2 * qc.y;
        acc[10] += w2 * qc.z;  acc[11] += w2 * qc.w;  acc[12] += w2 * hc;
    }

    // fold trace: slot 0 holds G = H0 + tr(H2)
    acc[0] += acc[4] + acc[8] + acc[12];

    // pack 13 bf16 into 28-B channel-major row
    unsigned short b[13];
#pragma unroll
    for (int p = 0; p < 13; ++p) b[p] = f2b(acc[p]);
    u32 w0 = (u32)b[0]  | ((u32)b[1]  << 16);
    u32 w1 = (u32)b[2]  | ((u32)b[3]  << 16);
    u32 w2 = (u32)b[4]  | ((u32)b[5]  << 16);
    u32 w3 = (u32)b[6]  | ((u32)b[7]  << 16);
    u32 w4 = (u32)b[8]  | ((u32)b[9]  << 16);
    u32 w5 = (u32)b[10] | ((u32)b[11] << 16);
    u32 w6 = (u32)b[12];

    char* dst = Hm + (size_t)n * 896 + i * 28;
    u32x4 q0; q0.x = w0; q0.y = w1; q0.z = w2; q0.w = w3;
    u32x2 q1; q1.x = w4; q1.y = w5;
    *(u32x4_a4*)dst        = q0;
    *(u32x2_a4*)(dst + 16) = q1;
    *(u32*)(dst + 24)      = w6;
}

// ---------------------------------------------------------------------------
// Gather r15: TWO WAVES per node (256-thr block = 2 nodes x 2 waves).
// Global par = wv*2 + (lane>>5) in {0..3}; each par group walks every 4th
// slot -> the serial per-wave latency chain halves (deg-8: 2 rounds vs 4)
// and wave TLP doubles (50K waves). Combine: shfl_xor(32) inside the wave,
// then a 3.3 KB LDS exchange (stride 13 -> conflict-free) + one barrier.
// Plain cached loads: r14 proved nontemporal loads REGRESS (-12% gather) —
// latency-bound loop, nt lengthens the critical path. Ledger: r7 manual
// pipeline -12%, r11 bucket-reg ~0, r12 unroll-2 ~0, r14 nt -12%.
// NOTE (r8): __launch_bounds__ min-waves clause forced 32 VGPR + spill (3x).
// ---------------------------------------------------------------------------
__global__ __launch_bounds__(256) void gather_kernel(
    const char* __restrict__ Hm, const int2* __restrict__ slots,
    const int* __restrict__ cursor,
    const float* __restrict__ ea0, const float* __restrict__ ea1,
    const float* __restrict__ ea2,
    float* __restrict__ out0, float* __restrict__ out1, float* __restrict__ out2)
{
    const int ln   = threadIdx.x >> 7;           // local node 0..1
    const int n    = blockIdx.x * 2 + ln;
    const int lane = threadIdx.x & 63;
    const int c    = lane & 31;
    const int wv   = (threadIdx.x >> 6) & 1;     // wave within node
    const int gpar = wv * 2 + (lane >> 5);       // 0..3

    const int draw = cursor[n];
    const int d    = draw < DMAX ? draw : DMAX;
    const u32 c28  = (u32)c * 28u;

    // whole bucket in registers: one coalesced load per wave, slot per lane
    const int2 my_sl = slots[(u32)n * DMAX + lane];

    float acc0 = 0.f, acc1[3] = {0.f, 0.f, 0.f};
    float acc2[9] = {0.f, 0.f, 0.f, 0.f, 0.f, 0.f, 0.f, 0.f, 0.f};

#pragma unroll 2
    for (int i = gpar; i < d; i += 4) {
        const u32 e    = (u32)__shfl(my_sl.x, i);
        const u32 recv = (u32)__shfl(my_sl.y, i);

        // 28-B bf16 Hm row, 3 wide loads (u32 offset math)
        const char* hmp = Hm + (recv * 896u + c28);
        const u32x4 q0 = *(const u32x4_a4*)hmp;
        const u32x2 q1 = *(const u32x2_a4*)(hmp + 16);
        const u32   q2 = *(const u32*)(hmp + 24);

        const float Gv = blo(q0.x);                  // slot0 = G
        float H1v[3], H2v[9];
        H1v[0] = bhi(q0.x); H1v[1] = blo(q0.y); H1v[2] = bhi(q0.y);
        H2v[0] = blo(q0.z); H2v[1] = bhi(q0.z); H2v[2] = blo(q0.w);
        H2v[3] = bhi(q0.w); H2v[4] = blo(q1.x); H2v[5] = bhi(q1.x);
        H2v[6] = blo(q1.y); H2v[7] = bhi(q1.y); H2v[8] = blo(q2);

        const float a0 = ea0[e];
        float a1[3], a2[9];
        {
            const f32x2 v = *(const f32x2_a4*)(ea1 + e * 3u);
            a1[0] = v.x; a1[1] = v.y; a1[2] = ea1[e * 3u + 2u];
            const f32x4 b0 = *(const f32x4_a4*)(ea2 + e * 9u);
            const f32x4 b1 = *(const f32x4_a4*)(ea2 + e * 9u + 4u);
            a2[0] = b0.x; a2[1] = b0.y; a2[2] = b0.z; a2[3] = b0.w;
            a2[4] = b1.x; a2[5] = b1.y; a2[6] = b1.z; a2[7] = b1.w;
            a2[8] = ea2[e * 9u + 8u];
        }

        edge_contract_g(Gv, H1v, H2v, a0, a1, a2, acc0, acc1, acc2);
    }

    // merge the wave's two par groups
    acc0 += __shfl_xor(acc0, 32);
#pragma unroll
    for (int a = 0; a < 3; ++a) acc1[a] += __shfl_xor(acc1[a], 32);
#pragma unroll
    for (int k = 0; k < 9; ++k) acc2[k] += __shfl_xor(acc2[k], 32);

    // cross-wave merge via LDS (stride 13: gcd(13,32)=1 -> conflict-free)
    __shared__ float red[2][32][13];
    if (wv == 1 && lane < 32) {
        float* r = red[ln][c];
        r[0] = acc0;
        r[1] = acc1[0]; r[2] = acc1[1]; r[3] = acc1[2];
#pragma unroll
        for (int k = 0; k < 9; ++k) r[4 + k] = acc2[k];
    }
    __syncthreads();
    if (wv == 0 && lane < 32) {
        const float* r = red[ln][c];
        acc0 += r[0];
        acc1[0] += r[1]; acc1[1] += r[2]; acc1[2] += r[3];
#pragma unroll
        for (int k = 0; k < 9; ++k) acc2[k] += r[4 + k];

        const u32 base = (u32)n * 32u + (u32)c;
        out0[base] = acc0;
        f32x2 o1; o1.x = acc1[0]; o1.y = acc1[1];
        *(f32x2_a4*)(out1 + base * 3u) = o1;
        out1[base * 3u + 2u] = acc1[2];
        f32x4 oa; oa.x = acc2[0]; oa.y = acc2[1]; oa.z = acc2[2]; oa.w = acc2[3];
        f32x4 ob; ob.x = acc2[4]; ob.y = acc2[5]; ob.z = acc2[6]; ob.w = acc2[7];
        *(f32x4_a4*)(out2 + base * 9u)      = oa;
        *(f32x4_a4*)(out2 + base * 9u + 4u) = ob;
        out2[base * 9u + 8u] = acc2[8];
    }
}

// ---------------------------------------------------------------------------
// Fallback (no workspace): fused per-edge mixing + contraction + atomics
// ---------------------------------------------------------------------------
__global__ __launch_bounds__(256) void fused_edge_kernel(
    const float* __restrict__ h0, const float* __restrict__ h1,
    const float* __restrict__ h2, const float* __restrict__ W,
    const float* __restrict__ ea0, const float* __restrict__ ea1,
    const float* __restrict__ ea2, const int* __restrict__ ei,
    float* __restrict__ out0, float* __restrict__ out1, float* __restrict__ out2)
{
    __shared__ float Wt[3 * 32 * 32];
    __shared__ float h_lds[8 * 417];

    const int tid = threadIdx.x;
#pragma unroll
    for (int k = 0; k < 12; ++k) {
        int q = tid + k * 256;
        int r = q >> 10;
        int j = (q >> 5) & 31;
        int i = q & 31;
        Wt[q] = W[r * 1024 + i * 32 + j];
    }

    const int g = tid >> 5;
    const int c = tid & 31;
    const int e = blockIdx.x * 8 + g;
    const int send = ei[e];
    const int recv = ei[N_EDGES + e];

    h_lds[g * 417 + c * 13 + 0] = h0[(size_t)recv * 32 + c];
#pragma unroll
    for (int a = 0; a < 3; ++a)
        h_lds[g * 417 + c * 13 + 1 + a] = h1[(size_t)recv * 96 + c * 3 + a];
#pragma unroll
    for (int k = 0; k < 9; ++k)
        h_lds[g * 417 + c * 13 + 4 + k] = h2[(size_t)recv * 288 + c * 9 + k];
    __syncthreads();

    float acc[13];
#pragma unroll
    for (int p = 0; p < 13; ++p) acc[p] = 0.f;
#pragma unroll 4
    for (int j = 0; j < 32; ++j) {
        const float w0 = Wt[          j * 32 + c];
        const float w1 = Wt[1024 +    j * 32 + c];
        const float w2 = Wt[2048 +    j * 32 + c];
        const float* hv = &h_lds[g * 417 + j * 13];
        acc[0] += w0 * hv[0];
#pragma unroll
        for (int p = 0; p < 3; ++p) acc[1 + p] += w1 * hv[1 + p];
#pragma unroll
        for (int p = 0; p < 9; ++p) acc[4 + p] += w2 * hv[4 + p];
    }

    const float a0 = ea0[e];
    float a1[3], a2[9];
#pragma unroll
    for (int a = 0; a < 3; ++a) a1[a] = ea1[(size_t)e * 3 + a];
#pragma unroll
    for (int k = 0; k < 9; ++k) a2[k] = ea2[(size_t)e * 9 + k];

    float acc0 = 0.f, acc1[3] = {0.f, 0.f, 0.f};
    float acc2[9] = {0.f, 0.f, 0.f, 0.f, 0.f, 0.f, 0.f, 0.f, 0.f};
    edge_contract(acc[0], &acc[1], &acc[4], a0, a1, a2, acc0, acc1, acc2);

    const size_t base = (size_t)send * 32 + c;
    atomicAdd(out0 + base, acc0);
#pragma unroll
    for (int a = 0; a < 3; ++a) atomicAdd(out1 + base * 3 + a, acc1[a]);
#pragma unroll
    for (int k = 0; k < 9; ++k) atomicAdd(out2 + base * 9 + k, acc2[k]);
}

// ---------------------------------------------------------------------------
extern "C" void kernel_launch(void* const* d_in, const int* in_sizes, int n_in,
                              void* d_out, int out_size, void* d_ws, size_t ws_size,
                              hipStream_t stream) {
    const float* h0  = (const float*)d_in[0];
    const float* h1  = (const float*)d_in[1];
    const float* h2  = (const float*)d_in[2];
    // d_in[3] = rel_pos, unused by the math
    const float* ea0 = (const float*)d_in[4];
    const float* ea1 = (const float*)d_in[5];
    const float* ea2 = (const float*)d_in[6];
    const float* W   = (const float*)d_in[7];
    const int*   ei  = (const int*)d_in[8];

    float* out0 = (float*)d_out;                               // [25000][32]
    float* out1 = out0 + (size_t)N_NODES * 32;                 // [25000][32][3]
    float* out2 = out1 + (size_t)N_NODES * 32 * 3;             // [25000][32][3][3]

    char* ws = (char*)d_ws;

    if (ws_size >= WS_NEEDED) {
        char* Hm     = ws;
        int2* slots  = (int2*)(ws + SLOTS_OFF);
        int*  cursor = (int*)(ws + CURSOR_OFF);

        hipMemsetAsync(cursor, 0, (size_t)N_NODES * 4, stream);
        mixscatter_kernel<<<3125 + 782, 256, 0, stream>>>(
            h0, h1, h2, W, ei, Hm, slots, cursor);
        gather_kernel<<<N_NODES / 2, 256, 0, stream>>>(
            Hm, slots, cursor, ea0, ea1, ea2, out0, out1, out2);
    } else {
        hipMemsetAsync(d_out, 0, (size_t)out_size * sizeof(float), stream);
        fused_edge_kernel<<<N_EDGES / 8, 256, 0, stream>>>(
            h0, h1, h2, W, ea0, ea1, ea2, ei, out0, out1, out2);
    }
}

// Round 16
// 90.701 us; speedup vs baseline: 1.0880x; 1.0880x over previous
//
#include <hip/hip_runtime.h>

#define N_NODES 25000
#define N_EDGES 200000
#define NC 32
#define DMAX 64            // bucket capacity; degrees are Poisson(8), max ~25

typedef unsigned int u32;
typedef u32   u32x4 __attribute__((ext_vector_type(4)));
typedef u32   u32x2 __attribute__((ext_vector_type(2)));
typedef float f32x2 __attribute__((ext_vector_type(2)));
typedef float f32x4 __attribute__((ext_vector_type(4)));
typedef u32x4 u32x4_a4 __attribute__((aligned(4)));
typedef u32x2 u32x2_a4 __attribute__((aligned(4)));
typedef f32x2 f32x2_a4 __attribute__((aligned(4)));
typedef f32x4 f32x4_a4 __attribute__((aligned(4)));

// ---------------------------------------------------------------------------
// Workspace layout (bytes)
//   Hm     : [25000][32 ch][14 ushort] bf16 (slot0 = G = H0+tr(H2))
//   slots  : [25000][64] int2   (.x = edge id, .y = recv id)
//   cursor : [25000] int
// ---------------------------------------------------------------------------
static constexpr size_t HM_BYTES   = (size_t)N_NODES * NC * 28;        // 22,400,000
static constexpr size_t SLOTS_OFF  = HM_BYTES;
static constexpr size_t CURSOR_OFF = SLOTS_OFF + (size_t)N_NODES * DMAX * 8;
static constexpr size_t WS_NEEDED  = CURSOR_OFF + (size_t)N_NODES * 4; // ~35.3 MB

__device__ __forceinline__ unsigned short f2b(float f) {
    union { float f; unsigned u; } v; v.f = f;
    unsigned r = v.u + 0x7FFFu + ((v.u >> 16) & 1u);
    return (unsigned short)(r >> 16);
}
__device__ __forceinline__ float blo(u32 u) { return __uint_as_float(u << 16); }
__device__ __forceinline__ float bhi(u32 u) { return __uint_as_float(u & 0xFFFF0000u); }

// ---------------------------------------------------------------------------
// Per-edge contraction, G-form (G = H0 + tr(H2) precomputed at mix time)
// ---------------------------------------------------------------------------
__device__ __forceinline__ void edge_contract_g(
    float G, const float H1v[3], const float H2v[9],
    float a0, const float a1[3], const float a2[9],
    float& acc0, float acc1[3], float acc2[9])
{
    const float t2 = a2[0] + a2[4] + a2[8];
    const float s  = a0 + t2;

    float sA[9], S2[9];
#pragma unroll
    for (int a = 0; a < 3; ++a)
#pragma unroll
        for (int b = 0; b < 3; ++b) {
            sA[a*3+b] = a2[a*3+b] + a2[b*3+a];
            S2[a*3+b] = H2v[a*3+b] + H2v[b*3+a];
        }

    float v0 = G * s;
#pragma unroll
    for (int a = 0; a < 3; ++a) v0 += H1v[a] * a1[a];
#pragma unroll
    for (int k = 0; k < 9; ++k) v0 += H2v[k] * sA[k];
    acc0 += v0;

#pragma unroll
    for (int a = 0; a < 3; ++a) {
        float v = G * a1[a] + H1v[a] * s;
#pragma unroll
        for (int b = 0; b < 3; ++b)
            v += sA[a*3+b] * H1v[b] + S2[a*3+b] * a1[b];
        acc1[a] += v;
    }

#pragma unroll
    for (int a = 0; a < 3; ++a)
#pragma unroll
        for (int b = 0; b < 3; ++b) {
            float v = G * a2[a*3+b] + H1v[a] * a1[b] + H2v[a*3+b] * s;
#pragma unroll
            for (int d = 0; d < 3; ++d)
                v += S2[a*3+d] * sA[d*3+b];
            acc2[a*3+b] += v;
        }
}

// original form for the no-workspace fallback
__device__ __forceinline__ void edge_contract(
    float H0v, const float H1v[3], const float H2v[9],
    float a0, const float a1[3], const float a2[9],
    float& acc0, float acc1[3], float acc2[9])
{
    const float T2 = H2v[0] + H2v[4] + H2v[8];
    edge_contract_g(H0v + T2, H1v, H2v, a0, a1, a2, acc0, acc1, acc2);
}

// ---------------------------------------------------------------------------
// Fused kernel: blocks [0,3125) = per-node channel mixing -> bf16 Hm
//               blocks [3125,3907) = bucket scatter of edges by send node
// cursor[] must be zeroed before this kernel (hipMemsetAsync).
// 8 nodes/block, 1 ch/thread, h_lds stride 16 floats/j — a wave spans 2
// nodes (node stride 512 floats, bank-aligned) -> 2-way LDS aliasing = FREE.
// r13's 16-nodes/block made it 4 nodes/wave -> 4-way conflict on every b128
// read (3.8M SQ_LDS_BANK_CONFLICT, mix 25->64 µs). Keep 2 nodes/wave.
// ---------------------------------------------------------------------------
__global__ __launch_bounds__(256) void mixscatter_kernel(
    const float* __restrict__ h0, const float* __restrict__ h1,
    const float* __restrict__ h2, const float* __restrict__ W,
    const int* __restrict__ ei,
    char* __restrict__ Hm, int2* __restrict__ slots, int* __restrict__ cursor)
{
    const int tid = threadIdx.x;

    if (blockIdx.x >= 3125) {            // ---- scatter part ----
        const int e = (blockIdx.x - 3125) * 256 + tid;
        if (e < N_EDGES) {
            const int send = ei[e];
            const int pos  = atomicAdd(&cursor[send], 1);
            if (pos < DMAX) {            // Poisson(8): deg>64 has P~1e-40
                int2 sl; sl.x = e; sl.y = ei[N_EDGES + e];
                slots[send * DMAX + pos] = sl;
            }
        }
        return;
    }

    // ---- mix part ----
    __shared__ float Wt[3 * 32 * 32];                 // Wt[r][j][i] = W[r][i][j]
    __shared__ __align__(16) float h_lds[8 * 512];    // [node][j*16 + p], p<13

    const int n0 = blockIdx.x * 8;

#pragma unroll
    for (int k = 0; k < 12; ++k) {
        int q = tid + k * 256;           // q = r*1024 + j*32 + i
        int r = q >> 10;
        int j = (q >> 5) & 31;
        int i = q & 31;
        Wt[q] = W[r * 1024 + i * 32 + j];
    }

    {
        int idx = tid;                   // h0: 256 floats
        h_lds[(idx >> 5) * 512 + (idx & 31) * 16 + 0] = h0[(size_t)n0 * 32 + idx];
    }
#pragma unroll
    for (int k = 0; k < 3; ++k) {        // h1: 768 floats
        int idx = tid + k * 256;
        int ln = idx / 96, rem = idx % 96;
        h_lds[ln * 512 + (rem / 3) * 16 + 1 + (rem % 3)] = h1[(size_t)n0 * 96 + idx];
    }
#pragma unroll
    for (int k = 0; k < 9; ++k) {        // h2: 2304 floats
        int idx = tid + k * 256;
        int ln = idx / 288, rem = idx % 288;
        h_lds[ln * 512 + (rem / 9) * 16 + 4 + (rem % 9)] = h2[(size_t)n0 * 288 + idx];
    }
    __syncthreads();

    const int ln = tid >> 5;
    const int i  = tid & 31;
    const int n  = n0 + ln;

    float acc[13];
#pragma unroll
    for (int p = 0; p < 13; ++p) acc[p] = 0.f;

#pragma unroll 4
    for (int j = 0; j < 32; ++j) {
        const float w0 = Wt[          j * 32 + i];
        const float w1 = Wt[1024 +    j * 32 + i];
        const float w2 = Wt[2048 +    j * 32 + i];
        const float* hv = &h_lds[ln * 512 + j * 16];
        const f32x4 qa = *(const f32x4*)(hv);        // p 0..3
        const f32x4 qb = *(const f32x4*)(hv + 4);    // p 4..7
        const f32x4 qc = *(const f32x4*)(hv + 8);    // p 8..11
        const float hc = hv[12];                     // p 12
        acc[0]  += w0 * qa.x;
        acc[1]  += w1 * qa.y;  acc[2]  += w1 * qa.z;  acc[3]  += w1 * qa.w;
        acc[4]  += w2 * qb.x;  acc[5]  += w2 * qb.y;  acc[6]  += w2 * qb.z;
        acc[7]  += w2 * qb.w;  acc[8]  += w2 * qc.x;  acc[9]  += w2 * qc.y;
        acc[10] += w2 * qc.z;  acc[11] += w2 * qc.w;  acc[12] += w2 * hc;
    }

    // fold trace: slot 0 holds G = H0 + tr(H2)
    acc[0] += acc[4] + acc[8] + acc[12];

    // pack 13 bf16 into 28-B channel-major row
    unsigned short b[13];
#pragma unroll
    for (int p = 0; p < 13; ++p) b[p] = f2b(acc[p]);
    u32 w0 = (u32)b[0]  | ((u32)b[1]  << 16);
    u32 w1 = (u32)b[2]  | ((u32)b[3]  << 16);
    u32 w2 = (u32)b[4]  | ((u32)b[5]  << 16);
    u32 w3 = (u32)b[6]  | ((u32)b[7]  << 16);
    u32 w4 = (u32)b[8]  | ((u32)b[9]  << 16);
    u32 w5 = (u32)b[10] | ((u32)b[11] << 16);
    u32 w6 = (u32)b[12];

    char* dst = Hm + (size_t)n * 896 + i * 28;
    u32x4 q0; q0.x = w0; q0.y = w1; q0.z = w2; q0.w = w3;
    u32x2 q1; q1.x = w4; q1.y = w5;
    *(u32x4_a4*)dst        = q0;
    *(u32x2_a4*)(dst + 16) = q1;
    *(u32*)(dst + 24)      = w6;
}

// ---------------------------------------------------------------------------
// Gather (r16 = exact r10 revert, the best-measured config: total 89.48 µs,
// gather 52.5 µs, FETCH 115 MB): one WAVE per node, two nodes per 128-thr
// block, plain rolled loop, direct slot loads, plain cached loads.
// CLOSED ledger of failed alternatives on this loop:
//   r7  manual SW pipeline      -12% (VGPR 48->56, occupancy drop)
//   r8  launch_bounds(,8)       -3x  (forced 32 VGPR -> scratch spill)
//   r11 bucket-in-regs + shfl    ~0  (+5 MB FETCH)
//   r12 #pragma unroll 2         ~0
//   r14 nontemporal loads       -12% (nt bypasses L2; latency-bound loop)
//   r15 2 waves/node + barrier  -20% (sync cost > halved latency chain)
// The loop is bound by dependent random L2/L3 round-trips; leave it alone.
// ---------------------------------------------------------------------------
__global__ __launch_bounds__(128) void gather_kernel(
    const char* __restrict__ Hm, const int2* __restrict__ slots,
    const int* __restrict__ cursor,
    const float* __restrict__ ea0, const float* __restrict__ ea1,
    const float* __restrict__ ea2,
    float* __restrict__ out0, float* __restrict__ out1, float* __restrict__ out2)
{
    const int n    = blockIdx.x * 2 + (threadIdx.x >> 6);
    const int lane = threadIdx.x & 63;
    const int c    = lane & 31;
    const int par  = lane >> 5;

    const int draw = cursor[n];
    const int d    = draw < DMAX ? draw : DMAX;
    const int2* sb = slots + (u32)n * DMAX;
    const u32 c28  = (u32)c * 28u;

    float acc0 = 0.f, acc1[3] = {0.f, 0.f, 0.f};
    float acc2[9] = {0.f, 0.f, 0.f, 0.f, 0.f, 0.f, 0.f, 0.f, 0.f};

#pragma unroll 1
    for (int i = par; i < d; i += 2) {
        const int2 sl  = sb[i];
        const u32  e   = (u32)sl.x;

        // 28-B bf16 Hm row, 3 wide loads (u32 offset math)
        const char* hmp = Hm + ((u32)sl.y * 896u + c28);
        const u32x4 q0 = *(const u32x4_a4*)hmp;
        const u32x2 q1 = *(const u32x2_a4*)(hmp + 16);
        const u32   q2 = *(const u32*)(hmp + 24);

        const float Gv = blo(q0.x);                  // slot0 = G
        float H1v[3], H2v[9];
        H1v[0] = bhi(q0.x); H1v[1] = blo(q0.y); H1v[2] = bhi(q0.y);
        H2v[0] = blo(q0.z); H2v[1] = bhi(q0.z); H2v[2] = blo(q0.w);
        H2v[3] = bhi(q0.w); H2v[4] = blo(q1.x); H2v[5] = bhi(q1.x);
        H2v[6] = blo(q1.y); H2v[7] = bhi(q1.y); H2v[8] = blo(q2);

        const float a0 = ea0[e];
        float a1[3], a2[9];
        {
            const f32x2 v = *(const f32x2_a4*)(ea1 + e * 3u);
            a1[0] = v.x; a1[1] = v.y; a1[2] = ea1[e * 3u + 2u];
            const f32x4 b0 = *(const f32x4_a4*)(ea2 + e * 9u);
            const f32x4 b1 = *(const f32x4_a4*)(ea2 + e * 9u + 4u);
            a2[0] = b0.x; a2[1] = b0.y; a2[2] = b0.z; a2[3] = b0.w;
            a2[4] = b1.x; a2[5] = b1.y; a2[6] = b1.z; a2[7] = b1.w;
            a2[8] = ea2[e * 9u + 8u];
        }

        edge_contract_g(Gv, H1v, H2v, a0, a1, a2, acc0, acc1, acc2);
    }

    // combine par=0 / par=1 halves
    acc0 += __shfl_xor(acc0, 32);
#pragma unroll
    for (int a = 0; a < 3; ++a) acc1[a] += __shfl_xor(acc1[a], 32);
#pragma unroll
    for (int k = 0; k < 9; ++k) acc2[k] += __shfl_xor(acc2[k], 32);

    if (par == 0) {
        const u32 base = (u32)n * 32u + (u32)c;
        out0[base] = acc0;
        f32x2 o1; o1.x = acc1[0]; o1.y = acc1[1];
        *(f32x2_a4*)(out1 + base * 3u) = o1;
        out1[base * 3u + 2u] = acc1[2];
        f32x4 oa; oa.x = acc2[0]; oa.y = acc2[1]; oa.z = acc2[2]; oa.w = acc2[3];
        f32x4 ob; ob.x = acc2[4]; ob.y = acc2[5]; ob.z = acc2[6]; ob.w = acc2[7];
        *(f32x4_a4*)(out2 + base * 9u)      = oa;
        *(f32x4_a4*)(out2 + base * 9u + 4u) = ob;
        out2[base * 9u + 8u] = acc2[8];
    }
}

// ---------------------------------------------------------------------------
// Fallback (no workspace): fused per-edge mixing + contraction + atomics
// ---------------------------------------------------------------------------
__global__ __launch_bounds__(256) void fused_edge_kernel(
    const float* __restrict__ h0, const float* __restrict__ h1,
    const float* __restrict__ h2, const float* __restrict__ W,
    const float* __restrict__ ea0, const float* __restrict__ ea1,
    const float* __restrict__ ea2, const int* __restrict__ ei,
    float* __restrict__ out0, float* __restrict__ out1, float* __restrict__ out2)
{
    __shared__ float Wt[3 * 32 * 32];
    __shared__ float h_lds[8 * 417];

    const int tid = threadIdx.x;
#pragma unroll
    for (int k = 0; k < 12; ++k) {
        int q = tid + k * 256;
        int r = q >> 10;
        int j = (q >> 5) & 31;
        int i = q & 31;
        Wt[q] = W[r * 1024 + i * 32 + j];
    }

    const int g = tid >> 5;
    const int c = tid & 31;
    const int e = blockIdx.x * 8 + g;
    const int send = ei[e];
    const int recv = ei[N_EDGES + e];

    h_lds[g * 417 + c * 13 + 0] = h0[(size_t)recv * 32 + c];
#pragma unroll
    for (int a = 0; a < 3; ++a)
        h_lds[g * 417 + c * 13 + 1 + a] = h1[(size_t)recv * 96 + c * 3 + a];
#pragma unroll
    for (int k = 0; k < 9; ++k)
        h_lds[g * 417 + c * 13 + 4 + k] = h2[(size_t)recv * 288 + c * 9 + k];
    __syncthreads();

    float acc[13];
#pragma unroll
    for (int p = 0; p < 13; ++p) acc[p] = 0.f;
#pragma unroll 4
    for (int j = 0; j < 32; ++j) {
        const float w0 = Wt[          j * 32 + c];
        const float w1 = Wt[1024 +    j * 32 + c];
        const float w2 = Wt[2048 +    j * 32 + c];
        const float* hv = &h_lds[g * 417 + j * 13];
        acc[0] += w0 * hv[0];
#pragma unroll
        for (int p = 0; p < 3; ++p) acc[1 + p] += w1 * hv[1 + p];
#pragma unroll
        for (int p = 0; p < 9; ++p) acc[4 + p] += w2 * hv[4 + p];
    }

    const float a0 = ea0[e];
    float a1[3], a2[9];
#pragma unroll
    for (int a = 0; a < 3; ++a) a1[a] = ea1[(size_t)e * 3 + a];
#pragma unroll
    for (int k = 0; k < 9; ++k) a2[k] = ea2[(size_t)e * 9 + k];

    float acc0 = 0.f, acc1[3] = {0.f, 0.f, 0.f};
    float acc2[9] = {0.f, 0.f, 0.f, 0.f, 0.f, 0.f, 0.f, 0.f, 0.f};
    edge_contract(acc[0], &acc[1], &acc[4], a0, a1, a2, acc0, acc1, acc2);

    const size_t base = (size_t)send * 32 + c;
    atomicAdd(out0 + base, acc0);
#pragma unroll
    for (int a = 0; a < 3; ++a) atomicAdd(out1 + base * 3 + a, acc1[a]);
#pragma unroll
    for (int k = 0; k < 9; ++k) atomicAdd(out2 + base * 9 + k, acc2[k]);
}

// ---------------------------------------------------------------------------
extern "C" void kernel_launch(void* const* d_in, const int* in_sizes, int n_in,
                              void* d_out, int out_size, void* d_ws, size_t ws_size,
                              hipStream_t stream) {
    const float* h0  = (const float*)d_in[0];
    const float* h1  = (const float*)d_in[1];
    const float* h2  = (const float*)d_in[2];
    // d_in[3] = rel_pos, unused by the math
    const float* ea0 = (const float*)d_in[4];
    const float* ea1 = (const float*)d_in[5];
    const float* ea2 = (const float*)d_in[6];
    const float* W   = (const float*)d_in[7];
    const int*   ei  = (const int*)d_in[8];

    float* out0 = (float*)d_out;                               // [25000][32]
    float* out1 = out0 + (size_t)N_NODES * 32;                 // [25000][32][3]
    float* out2 = out1 + (size_t)N_NODES * 32 * 3;             // [25000][32][3][3]

    char* ws = (char*)d_ws;

    if (ws_size >= WS_NEEDED) {
        char* Hm     = ws;
        int2* slots  = (int2*)(ws + SLOTS_OFF);
        int*  cursor = (int*)(ws + CURSOR_OFF);

        hipMemsetAsync(cursor, 0, (size_t)N_NODES * 4, stream);
        mixscatter_kernel<<<3125 + 782, 256, 0, stream>>>(
            h0, h1, h2, W, ei, Hm, slots, cursor);
        gather_kernel<<<N_NODES / 2, 128, 0, stream>>>(
            Hm, slots, cursor, ea0, ea1, ea2, out0, out1, out2);
    } else {
        hipMemsetAsync(d_out, 0, (size_t)out_size * sizeof(float), stream);
        fused_edge_kernel<<<N_EDGES / 8, 256, 0, stream>>>(
            h0, h1, h2, W, ea0, ea1, ea2, ei, out0, out1, out2);
    }
}

// Round 17
// 87.204 us; speedup vs baseline: 1.1316x; 1.0401x over previous
//
#include <hip/hip_runtime.h>

#define N_NODES 25000
#define N_EDGES 200000
#define NC 32
#define DMAX 64            // thin-tier bucket capacity
#define DMAXF 40           // fat-tier capacity; Poisson(8) P(deg>40) ~ 8e-15

typedef unsigned int u32;
typedef u32   u32x4 __attribute__((ext_vector_type(4)));
typedef u32   u32x2 __attribute__((ext_vector_type(2)));
typedef float f32x2 __attribute__((ext_vector_type(2)));
typedef float f32x4 __attribute__((ext_vector_type(4)));
typedef u32x4 u32x4_a4 __attribute__((aligned(4)));
typedef u32x2 u32x2_a4 __attribute__((aligned(4)));
typedef f32x2 f32x2_a4 __attribute__((aligned(4)));
typedef f32x4 f32x4_a4 __attribute__((aligned(4)));

// ---------------------------------------------------------------------------
// Workspace layouts (bytes)
// FAT tier (preferred, ~86.5 MB):
//   Hm       : [25000][32 ch][14 ushort] bf16 (slot0 = G)   = 22,400,000
//   fatslots : [25000][40][16 float]  (recv+attrs packed)   = 64,000,000
//   cursor   : [25000] int                                  =    100,000
// THIN tier (r16 fallback, ~35.3 MB): Hm + slots[25000][64] int2 + cursor
// ---------------------------------------------------------------------------
static constexpr size_t HM_BYTES    = (size_t)N_NODES * NC * 28;       // 22,400,000
// thin
static constexpr size_t SLOTS_OFF   = HM_BYTES;
static constexpr size_t CURSOR_OFF  = SLOTS_OFF + (size_t)N_NODES * DMAX * 8;
static constexpr size_t WS_NEEDED   = CURSOR_OFF + (size_t)N_NODES * 4;
// fat
static constexpr size_t FAT_OFF     = HM_BYTES;                        // 64-aligned
static constexpr size_t CURSORF_OFF = FAT_OFF + (size_t)N_NODES * DMAXF * 64;
static constexpr size_t WS_FAT      = CURSORF_OFF + (size_t)N_NODES * 4;

__device__ __forceinline__ unsigned short f2b(float f) {
    union { float f; unsigned u; } v; v.f = f;
    unsigned r = v.u + 0x7FFFu + ((v.u >> 16) & 1u);
    return (unsigned short)(r >> 16);
}
__device__ __forceinline__ float blo(u32 u) { return __uint_as_float(u << 16); }
__device__ __forceinline__ float bhi(u32 u) { return __uint_as_float(u & 0xFFFF0000u); }

// ---------------------------------------------------------------------------
// Per-edge contraction, G-form (G = H0 + tr(H2) precomputed at mix time)
// ---------------------------------------------------------------------------
__device__ __forceinline__ void edge_contract_g(
    float G, const float H1v[3], const float H2v[9],
    float a0, const float a1[3], const float a2[9],
    float& acc0, float acc1[3], float acc2[9])
{
    const float t2 = a2[0] + a2[4] + a2[8];
    const float s  = a0 + t2;

    float sA[9], S2[9];
#pragma unroll
    for (int a = 0; a < 3; ++a)
#pragma unroll
        for (int b = 0; b < 3; ++b) {
            sA[a*3+b] = a2[a*3+b] + a2[b*3+a];
            S2[a*3+b] = H2v[a*3+b] + H2v[b*3+a];
        }

    float v0 = G * s;
#pragma unroll
    for (int a = 0; a < 3; ++a) v0 += H1v[a] * a1[a];
#pragma unroll
    for (int k = 0; k < 9; ++k) v0 += H2v[k] * sA[k];
    acc0 += v0;

#pragma unroll
    for (int a = 0; a < 3; ++a) {
        float v = G * a1[a] + H1v[a] * s;
#pragma unroll
        for (int b = 0; b < 3; ++b)
            v += sA[a*3+b] * H1v[b] + S2[a*3+b] * a1[b];
        acc1[a] += v;
    }

#pragma unroll
    for (int a = 0; a < 3; ++a)
#pragma unroll
        for (int b = 0; b < 3; ++b) {
            float v = G * a2[a*3+b] + H1v[a] * a1[b] + H2v[a*3+b] * s;
#pragma unroll
            for (int d = 0; d < 3; ++d)
                v += S2[a*3+d] * sA[d*3+b];
            acc2[a*3+b] += v;
        }
}

__device__ __forceinline__ void edge_contract(
    float H0v, const float H1v[3], const float H2v[9],
    float a0, const float a1[3], const float a2[9],
    float& acc0, float acc1[3], float acc2[9])
{
    const float T2 = H2v[0] + H2v[4] + H2v[8];
    edge_contract_g(H0v + T2, H1v, H2v, a0, a1, a2, acc0, acc1, acc2);
}

// ---------------------------------------------------------------------------
// Shared mix body (r16-proven: 8 nodes/block, 1 ch/thread, stride-16 LDS —
// wave spans 2 nodes -> 2-way aliasing = free. r13's 16-node variant caused
// 4-way conflicts on every b128 read; do not raise nodes/wave past 2).
// ---------------------------------------------------------------------------
__device__ __forceinline__ void mix_body(
    const float* __restrict__ h0, const float* __restrict__ h1,
    const float* __restrict__ h2, const float* __restrict__ W,
    char* __restrict__ Hm)
{
    __shared__ float Wt[3 * 32 * 32];                 // Wt[r][j][i] = W[r][i][j]
    __shared__ __align__(16) float h_lds[8 * 512];    // [node][j*16 + p], p<13

    const int tid = threadIdx.x;
    const int n0  = blockIdx.x * 8;

#pragma unroll
    for (int k = 0; k < 12; ++k) {
        int q = tid + k * 256;           // q = r*1024 + j*32 + i
        int r = q >> 10;
        int j = (q >> 5) & 31;
        int i = q & 31;
        Wt[q] = W[r * 1024 + i * 32 + j];
    }

    {
        int idx = tid;                   // h0: 256 floats
        h_lds[(idx >> 5) * 512 + (idx & 31) * 16 + 0] = h0[(size_t)n0 * 32 + idx];
    }
#pragma unroll
    for (int k = 0; k < 3; ++k) {        // h1: 768 floats
        int idx = tid + k * 256;
        int ln = idx / 96, rem = idx % 96;
        h_lds[ln * 512 + (rem / 3) * 16 + 1 + (rem % 3)] = h1[(size_t)n0 * 96 + idx];
    }
#pragma unroll
    for (int k = 0; k < 9; ++k) {        // h2: 2304 floats
        int idx = tid + k * 256;
        int ln = idx / 288, rem = idx % 288;
        h_lds[ln * 512 + (rem / 9) * 16 + 4 + (rem % 9)] = h2[(size_t)n0 * 288 + idx];
    }
    __syncthreads();

    const int ln = tid >> 5;
    const int i  = tid & 31;
    const int n  = n0 + ln;

    float acc[13];
#pragma unroll
    for (int p = 0; p < 13; ++p) acc[p] = 0.f;

#pragma unroll 4
    for (int j = 0; j < 32; ++j) {
        const float w0 = Wt[          j * 32 + i];
        const float w1 = Wt[1024 +    j * 32 + i];
        const float w2 = Wt[2048 +    j * 32 + i];
        const float* hv = &h_lds[ln * 512 + j * 16];
        const f32x4 qa = *(const f32x4*)(hv);        // p 0..3
        const f32x4 qb = *(const f32x4*)(hv + 4);    // p 4..7
        const f32x4 qc = *(const f32x4*)(hv + 8);    // p 8..11
        const float hc = hv[12];                     // p 12
        acc[0]  += w0 * qa.x;
        acc[1]  += w1 * qa.y;  acc[2]  += w1 * qa.z;  acc[3]  += w1 * qa.w;
        acc[4]  += w2 * qb.x;  acc[5]  += w2 * qb.y;  acc[6]  += w2 * qb.z;
        acc[7]  += w2 * qb.w;  acc[8]  += w2 * qc.x;  acc[9]  += w2 * qc.y;
        acc[10] += w2 * qc.z;  acc[11] += w2 * qc.w;  acc[12] += w2 * hc;
    }

    // fold trace: slot 0 holds G = H0 + tr(H2)
    acc[0] += acc[4] + acc[8] + acc[12];

    unsigned short b[13];
#pragma unroll
    for (int p = 0; p < 13; ++p) b[p] = f2b(acc[p]);
    u32 w0 = (u32)b[0]  | ((u32)b[1]  << 16);
    u32 w1 = (u32)b[2]  | ((u32)b[3]  << 16);
    u32 w2 = (u32)b[4]  | ((u32)b[5]  << 16);
    u32 w3 = (u32)b[6]  | ((u32)b[7]  << 16);
    u32 w4 = (u32)b[8]  | ((u32)b[9]  << 16);
    u32 w5 = (u32)b[10] | ((u32)b[11] << 16);
    u32 w6 = (u32)b[12];

    char* dst = Hm + (size_t)n * 896 + i * 28;
    u32x4 q0; q0.x = w0; q0.y = w1; q0.z = w2; q0.w = w3;
    u32x2 q1; q1.x = w4; q1.y = w5;
    *(u32x4_a4*)dst        = q0;
    *(u32x2_a4*)(dst + 16) = q1;
    *(u32*)(dst + 24)      = w6;
}

// ---------------------------------------------------------------------------
// FAT tier: scatter packs recv + all attrs into a 64-B slot. Attr reads at
// scatter time are COALESCED (thread id = e); the gather loop then never
// touches ea0/ea1/ea2 (its random 52-B attr reads were ~60 MB of FETCH).
// Slot layout: [recv, a0, a1x, a1y | a1z, a2_0..2 | a2_3..6 | a2_7, a2_8, -, -]
// ---------------------------------------------------------------------------
__global__ __launch_bounds__(256) void mixscatter_fat_kernel(
    const float* __restrict__ h0, const float* __restrict__ h1,
    const float* __restrict__ h2, const float* __restrict__ W,
    const int* __restrict__ ei,
    const float* __restrict__ ea0, const float* __restrict__ ea1,
    const float* __restrict__ ea2,
    char* __restrict__ Hm, float* __restrict__ fat, int* __restrict__ cursor)
{
    if (blockIdx.x >= 3125) {            // ---- scatter part ----
        const int e = (blockIdx.x - 3125) * 256 + threadIdx.x;
        if (e < N_EDGES) {
            const int send = ei[e];
            const int pos  = atomicAdd(&cursor[send], 1);
            if (pos < DMAXF) {
                const float a1x = ea1[(size_t)e * 3];
                const float a1y = ea1[(size_t)e * 3 + 1];
                const float a1z = ea1[(size_t)e * 3 + 2];
                const f32x4 b0 = *(const f32x4_a4*)(ea2 + (size_t)e * 9);
                const f32x4 b1 = *(const f32x4_a4*)(ea2 + (size_t)e * 9 + 4);
                const float a28 = ea2[(size_t)e * 9 + 8];

                f32x4 s0; s0.x = __int_as_float(ei[N_EDGES + e]);
                s0.y = ea0[e]; s0.z = a1x; s0.w = a1y;
                f32x4 s1; s1.x = a1z; s1.y = b0.x; s1.z = b0.y; s1.w = b0.z;
                f32x4 s2; s2.x = b0.w; s2.y = b1.x; s2.z = b1.y; s2.w = b1.z;
                f32x4 s3; s3.x = b1.w; s3.y = a28; s3.z = 0.f; s3.w = 0.f;

                float* dst = fat + ((size_t)send * DMAXF + pos) * 16;
                *(f32x4_a4*)(dst)      = s0;
                *(f32x4_a4*)(dst + 4)  = s1;
                *(f32x4_a4*)(dst + 8)  = s2;
                *(f32x4_a4*)(dst + 12) = s3;
            }
        }
        return;
    }
    mix_body(h0, h1, h2, W, Hm);
}

// ---------------------------------------------------------------------------
// FAT gather: r16 loop structure (proven best; closed failure ledger:
// r7 pipeline -12%, r8 launch_bounds spill -3x, r11 bucket-reg ~0,
// r12 unroll-2 ~0, r14 nt-loads -12%, r15 wave-split -20%) with attr loads
// replaced by one sequential 64-B fat-slot read (broadcast across lanes).
// ---------------------------------------------------------------------------
__global__ __launch_bounds__(128) void gather_fat_kernel(
    const char* __restrict__ Hm, const float* __restrict__ fat,
    const int* __restrict__ cursor,
    float* __restrict__ out0, float* __restrict__ out1, float* __restrict__ out2)
{
    const int n    = blockIdx.x * 2 + (threadIdx.x >> 6);
    const int lane = threadIdx.x & 63;
    const int c    = lane & 31;
    const int par  = lane >> 5;

    const int draw = cursor[n];
    const int d    = draw < DMAXF ? draw : DMAXF;
    const float* fb = fat + (size_t)n * DMAXF * 16;
    const u32 c28  = (u32)c * 28u;

    float acc0 = 0.f, acc1[3] = {0.f, 0.f, 0.f};
    float acc2[9] = {0.f, 0.f, 0.f, 0.f, 0.f, 0.f, 0.f, 0.f, 0.f};

#pragma unroll 1
    for (int i = par; i < d; i += 2) {
        const float* fp = fb + (u32)i * 16u;
        const f32x4 s0 = *(const f32x4_a4*)(fp);
        const f32x4 s1 = *(const f32x4_a4*)(fp + 4);
        const f32x4 s2 = *(const f32x4_a4*)(fp + 8);
        const f32x4 s3 = *(const f32x4_a4*)(fp + 12);

        const u32 recv = (u32)__float_as_int(s0.x);

        // 28-B bf16 Hm row, 3 wide loads (u32 offset math)
        const char* hmp = Hm + (recv * 896u + c28);
        const u32x4 q0 = *(const u32x4_a4*)hmp;
        const u32x2 q1 = *(const u32x2_a4*)(hmp + 16);
        const u32   q2 = *(const u32*)(hmp + 24);

        const float Gv = blo(q0.x);                  // slot0 = G
        float H1v[3], H2v[9];
        H1v[0] = bhi(q0.x); H1v[1] = blo(q0.y); H1v[2] = bhi(q0.y);
        H2v[0] = blo(q0.z); H2v[1] = bhi(q0.z); H2v[2] = blo(q0.w);
        H2v[3] = bhi(q0.w); H2v[4] = blo(q1.x); H2v[5] = bhi(q1.x);
        H2v[6] = blo(q1.y); H2v[7] = bhi(q1.y); H2v[8] = blo(q2);

        const float a0 = s0.y;
        float a1[3], a2[9];
        a1[0] = s0.z; a1[1] = s0.w; a1[2] = s1.x;
        a2[0] = s1.y; a2[1] = s1.z; a2[2] = s1.w; a2[3] = s2.x;
        a2[4] = s2.y; a2[5] = s2.z; a2[6] = s2.w; a2[7] = s3.x; a2[8] = s3.y;

        edge_contract_g(Gv, H1v, H2v, a0, a1, a2, acc0, acc1, acc2);
    }

    // combine par=0 / par=1 halves
    acc0 += __shfl_xor(acc0, 32);
#pragma unroll
    for (int a = 0; a < 3; ++a) acc1[a] += __shfl_xor(acc1[a], 32);
#pragma unroll
    for (int k = 0; k < 9; ++k) acc2[k] += __shfl_xor(acc2[k], 32);

    if (par == 0) {
        const u32 base = (u32)n * 32u + (u32)c;
        out0[base] = acc0;
        f32x2 o1; o1.x = acc1[0]; o1.y = acc1[1];
        *(f32x2_a4*)(out1 + base * 3u) = o1;
        out1[base * 3u + 2u] = acc1[2];
        f32x4 oa; oa.x = acc2[0]; oa.y = acc2[1]; oa.z = acc2[2]; oa.w = acc2[3];
        f32x4 ob; ob.x = acc2[4]; ob.y = acc2[5]; ob.z = acc2[6]; ob.w = acc2[7];
        *(f32x4_a4*)(out2 + base * 9u)      = oa;
        *(f32x4_a4*)(out2 + base * 9u + 4u) = ob;
        out2[base * 9u + 8u] = acc2[8];
    }
}

// ---------------------------------------------------------------------------
// THIN tier (exact r16 path — proven 89.5-90.7 µs)
// ---------------------------------------------------------------------------
__global__ __launch_bounds__(256) void mixscatter_kernel(
    const float* __restrict__ h0, const float* __restrict__ h1,
    const float* __restrict__ h2, const float* __restrict__ W,
    const int* __restrict__ ei,
    char* __restrict__ Hm, int2* __restrict__ slots, int* __restrict__ cursor)
{
    if (blockIdx.x >= 3125) {            // ---- scatter part ----
        const int e = (blockIdx.x - 3125) * 256 + threadIdx.x;
        if (e < N_EDGES) {
            const int send = ei[e];
            const int pos  = atomicAdd(&cursor[send], 1);
            if (pos < DMAX) {
                int2 sl; sl.x = e; sl.y = ei[N_EDGES + e];
                slots[send * DMAX + pos] = sl;
            }
        }
        return;
    }
    mix_body(h0, h1, h2, W, Hm);
}

__global__ __launch_bounds__(128) void gather_kernel(
    const char* __restrict__ Hm, const int2* __restrict__ slots,
    const int* __restrict__ cursor,
    const float* __restrict__ ea0, const float* __restrict__ ea1,
    const float* __restrict__ ea2,
    float* __restrict__ out0, float* __restrict__ out1, float* __restrict__ out2)
{
    const int n    = blockIdx.x * 2 + (threadIdx.x >> 6);
    const int lane = threadIdx.x & 63;
    const int c    = lane & 31;
    const int par  = lane >> 5;

    const int draw = cursor[n];
    const int d    = draw < DMAX ? draw : DMAX;
    const int2* sb = slots + (u32)n * DMAX;
    const u32 c28  = (u32)c * 28u;

    float acc0 = 0.f, acc1[3] = {0.f, 0.f, 0.f};
    float acc2[9] = {0.f, 0.f, 0.f, 0.f, 0.f, 0.f, 0.f, 0.f, 0.f};

#pragma unroll 1
    for (int i = par; i < d; i += 2) {
        const int2 sl  = sb[i];
        const u32  e   = (u32)sl.x;

        const char* hmp = Hm + ((u32)sl.y * 896u + c28);
        const u32x4 q0 = *(const u32x4_a4*)hmp;
        const u32x2 q1 = *(const u32x2_a4*)(hmp + 16);
        const u32   q2 = *(const u32*)(hmp + 24);

        const float Gv = blo(q0.x);
        float H1v[3], H2v[9];
        H1v[0] = bhi(q0.x); H1v[1] = blo(q0.y); H1v[2] = bhi(q0.y);
        H2v[0] = blo(q0.z); H2v[1] = bhi(q0.z); H2v[2] = blo(q0.w);
        H2v[3] = bhi(q0.w); H2v[4] = blo(q1.x); H2v[5] = bhi(q1.x);
        H2v[6] = blo(q1.y); H2v[7] = bhi(q1.y); H2v[8] = blo(q2);

        const float a0 = ea0[e];
        float a1[3], a2[9];
        {
            const f32x2 v = *(const f32x2_a4*)(ea1 + e * 3u);
            a1[0] = v.x; a1[1] = v.y; a1[2] = ea1[e * 3u + 2u];
            const f32x4 b0 = *(const f32x4_a4*)(ea2 + e * 9u);
            const f32x4 b1 = *(const f32x4_a4*)(ea2 + e * 9u + 4u);
            a2[0] = b0.x; a2[1] = b0.y; a2[2] = b0.z; a2[3] = b0.w;
            a2[4] = b1.x; a2[5] = b1.y; a2[6] = b1.z; a2[7] = b1.w;
            a2[8] = ea2[e * 9u + 8u];
        }

        edge_contract_g(Gv, H1v, H2v, a0, a1, a2, acc0, acc1, acc2);
    }

    acc0 += __shfl_xor(acc0, 32);
#pragma unroll
    for (int a = 0; a < 3; ++a) acc1[a] += __shfl_xor(acc1[a], 32);
#pragma unroll
    for (int k = 0; k < 9; ++k) acc2[k] += __shfl_xor(acc2[k], 32);

    if (par == 0) {
        const u32 base = (u32)n * 32u + (u32)c;
        out0[base] = acc0;
        f32x2 o1; o1.x = acc1[0]; o1.y = acc1[1];
        *(f32x2_a4*)(out1 + base * 3u) = o1;
        out1[base * 3u + 2u] = acc1[2];
        f32x4 oa; oa.x = acc2[0]; oa.y = acc2[1]; oa.z = acc2[2]; oa.w = acc2[3];
        f32x4 ob; ob.x = acc2[4]; ob.y = acc2[5]; ob.z = acc2[6]; ob.w = acc2[7];
        *(f32x4_a4*)(out2 + base * 9u)      = oa;
        *(f32x4_a4*)(out2 + base * 9u + 4u) = ob;
        out2[base * 9u + 8u] = acc2[8];
    }
}

// ---------------------------------------------------------------------------
// Fallback (no workspace): fused per-edge mixing + contraction + atomics
// ---------------------------------------------------------------------------
__global__ __launch_bounds__(256) void fused_edge_kernel(
    const float* __restrict__ h0, const float* __restrict__ h1,
    const float* __restrict__ h2, const float* __restrict__ W,
    const float* __restrict__ ea0, const float* __restrict__ ea1,
    const float* __restrict__ ea2, const int* __restrict__ ei,
    float* __restrict__ out0, float* __restrict__ out1, float* __restrict__ out2)
{
    __shared__ float Wt[3 * 32 * 32];
    __shared__ float h_lds[8 * 417];

    const int tid = threadIdx.x;
#pragma unroll
    for (int k = 0; k < 12; ++k) {
        int q = tid + k * 256;
        int r = q >> 10;
        int j = (q >> 5) & 31;
        int i = q & 31;
        Wt[q] = W[r * 1024 + i * 32 + j];
    }

    const int g = tid >> 5;
    const int c = tid & 31;
    const int e = blockIdx.x * 8 + g;
    const int send = ei[e];
    const int recv = ei[N_EDGES + e];

    h_lds[g * 417 + c * 13 + 0] = h0[(size_t)recv * 32 + c];
#pragma unroll
    for (int a = 0; a < 3; ++a)
        h_lds[g * 417 + c * 13 + 1 + a] = h1[(size_t)recv * 96 + c * 3 + a];
#pragma unroll
    for (int k = 0; k < 9; ++k)
        h_lds[g * 417 + c * 13 + 4 + k] = h2[(size_t)recv * 288 + c * 9 + k];
    __syncthreads();

    float acc[13];
#pragma unroll
    for (int p = 0; p < 13; ++p) acc[p] = 0.f;
#pragma unroll 4
    for (int j = 0; j < 32; ++j) {
        const float w0 = Wt[          j * 32 + c];
        const float w1 = Wt[1024 +    j * 32 + c];
        const float w2 = Wt[2048 +    j * 32 + c];
        const float* hv = &h_lds[g * 417 + j * 13];
        acc[0] += w0 * hv[0];
#pragma unroll
        for (int p = 0; p < 3; ++p) acc[1 + p] += w1 * hv[1 + p];
#pragma unroll
        for (int p = 0; p < 9; ++p) acc[4 + p] += w2 * hv[4 + p];
    }

    const float a0 = ea0[e];
    float a1[3], a2[9];
#pragma unroll
    for (int a = 0; a < 3; ++a) a1[a] = ea1[(size_t)e * 3 + a];
#pragma unroll
    for (int k = 0; k < 9; ++k) a2[k] = ea2[(size_t)e * 9 + k];

    float acc0 = 0.f, acc1[3] = {0.f, 0.f, 0.f};
    float acc2[9] = {0.f, 0.f, 0.f, 0.f, 0.f, 0.f, 0.f, 0.f, 0.f};
    edge_contract(acc[0], &acc[1], &acc[4], a0, a1, a2, acc0, acc1, acc2);

    const size_t base = (size_t)send * 32 + c;
    atomicAdd(out0 + base, acc0);
#pragma unroll
    for (int a = 0; a < 3; ++a) atomicAdd(out1 + base * 3 + a, acc1[a]);
#pragma unroll
    for (int k = 0; k < 9; ++k) atomicAdd(out2 + base * 9 + k, acc2[k]);
}

// ---------------------------------------------------------------------------
extern "C" void kernel_launch(void* const* d_in, const int* in_sizes, int n_in,
                              void* d_out, int out_size, void* d_ws, size_t ws_size,
                              hipStream_t stream) {
    const float* h0  = (const float*)d_in[0];
    const float* h1  = (const float*)d_in[1];
    const float* h2  = (const float*)d_in[2];
    // d_in[3] = rel_pos, unused by the math
    const float* ea0 = (const float*)d_in[4];
    const float* ea1 = (const float*)d_in[5];
    const float* ea2 = (const float*)d_in[6];
    const float* W   = (const float*)d_in[7];
    const int*   ei  = (const int*)d_in[8];

    float* out0 = (float*)d_out;                               // [25000][32]
    float* out1 = out0 + (size_t)N_NODES * 32;                 // [25000][32][3]
    float* out2 = out1 + (size_t)N_NODES * 32 * 3;             // [25000][32][3][3]

    char* ws = (char*)d_ws;

    if (ws_size >= WS_FAT) {
        char*  Hm     = ws;
        float* fat    = (float*)(ws + FAT_OFF);
        int*   cursor = (int*)(ws + CURSORF_OFF);

        hipMemsetAsync(cursor, 0, (size_t)N_NODES * 4, stream);
        mixscatter_fat_kernel<<<3125 + 782, 256, 0, stream>>>(
            h0, h1, h2, W, ei, ea0, ea1, ea2, Hm, fat, cursor);
        gather_fat_kernel<<<N_NODES / 2, 128, 0, stream>>>(
            Hm, fat, cursor, out0, out1, out2);
    } else if (ws_size >= WS_NEEDED) {
        char* Hm     = ws;
        int2* slots  = (int2*)(ws + SLOTS_OFF);
        int*  cursor = (int*)(ws + CURSOR_OFF);

        hipMemsetAsync(cursor, 0, (size_t)N_NODES * 4, stream);
        mixscatter_kernel<<<3125 + 782, 256, 0, stream>>>(
            h0, h1, h2, W, ei, Hm, slots, cursor);
        gather_kernel<<<N_NODES / 2, 128, 0, stream>>>(
            Hm, slots, cursor, ea0, ea1, ea2, out0, out1, out2);
    } else {
        hipMemsetAsync(d_out, 0, (size_t)out_size * sizeof(float), stream);
        fused_edge_kernel<<<N_EDGES / 8, 256, 0, stream>>>(
            h0, h1, h2, W, ea0, ea1, ea2, ei, out0, out1, out2);
    }
}